// Round 9
// baseline (190.138 us; speedup 1.0000x reference)
//
#include <hip/hip_runtime.h>
#include <math.h>

#define Bn   128
#define Rn   1152
#define CIn  8
#define Cn   10
#define On   16
#define BO   2048      // Bn*On
#define CBO  20480     // Cn*BO
#define RC   12        // r's per r-seg wave (pass1)
#define GRID1 480      // 10c * 2bh * 24segq
#define NT1  512       // pass1: 8 waves = 4 r-segs x 2 o-halves
#define NBLK2 320      // stream passes: 320 blocks * 4 waves = 1280 (c,b) rows
#define NT2  256
#define UROW 18432     // Rn*On floats per (c,b) row
#define LOG2E 1.4426950408889634f
#define INV_R 8.6805555e-4f   // 1/1152

// ws layout: XT[1179648] | TL[102416] | U[23592960]  (~99.5 MB total)
// TL: T1 | T2 | L2 | T3 | L3 (20480 each) | ticket

// ---- transpose x[b][r][i] -> XT[r][g][b][q]  (i = g*4+q) + zero TL/ticket
__global__ __launch_bounds__(256)
void transpose_x(const float* __restrict__ X, float* __restrict__ XT,
                 float* __restrict__ TL)
{
    const int r = blockIdx.x;
    const int b = threadIdx.x & 127;
    const int g = threadIdx.x >> 7;
    float4 v = *(const float4*)(X + (size_t)b * (Rn * CIn) + r * CIn + g * 4);
    ((float4*)XT)[r * 256 + g * 128 + b] = v;
    const int zi = blockIdx.x * 256 + threadIdx.x;
    if (zi < 25604) ((float4*)TL)[zi] = make_float4(0.f, 0.f, 0.f, 0.f);
}

// ---- pass1: compute u, store it to global, atomic-merge T1 ------------------
__global__ __launch_bounds__(NT1, 4)
void pass1_kernel(const float* __restrict__ XT, const float* __restrict__ W,
                  float* __restrict__ TL, float* __restrict__ U)
{
    __shared__ __align__(16) float smem[8 * 64 * 18];   // W[48][128] / red overlay
    float (*wlds)[128]   = (float (*)[128])smem;
    float (*red)[64][18] = (float (*)[64][18])smem;
    float* T1 = TL;

    const int blk  = blockIdx.x;
    const int c    = blk / 48;
    const int rem  = blk - c * 48;
    const int bh   = rem / 24;
    const int segq = rem - bh * 24;
    const int tid  = threadIdx.x;
    const int w    = tid >> 6;
    const int lane = tid & 63;
    const int b    = bh * 64 + lane;
    const int oh   = w >> 2;
    const int sw   = w & 3;
    const int ohs  = __builtin_amdgcn_readfirstlane(oh * 8);

    // stage W tile: 48 rows * 128 floats
    {
        const float4* gw4 = (const float4*)(W + (size_t)(c * Rn + segq * 48) * 128);
        float4* sw4 = (float4*)smem;
        #pragma unroll
        for (int k = 0; k < 3; ++k)
            sw4[tid + k * 512] = gw4[tid + k * 512];
    }

    float tacc[8];
    #pragma unroll
    for (int o = 0; o < 8; ++o) tacc[o] = 0.0f;

    __syncthreads();

    const float4* XT4 = (const float4*)XT;
    const float4* xp  = XT4 + (size_t)(segq * 48 + sw * RC) * 256 + b;
    float* ubase = U + ((size_t)(c * Bn + b) * Rn + (segq * 48 + sw * RC)) * On + ohs;

    float4 xa = xp[0];
    float4 xb = xp[128];
    for (int rr = 0; rr < RC; ++rr) {
        const int nx = (rr + 1 < RC) ? (rr + 1) : rr;   // prefetch next x
        const float4 nxa = xp[nx * 256];
        const float4 nxb = xp[nx * 256 + 128];
        const int lrow = sw * RC + rr;
        const float xi[8] = { xa.x, xa.y, xa.z, xa.w, xb.x, xb.y, xb.z, xb.w };

        float u[8];
        #pragma unroll
        for (int o = 0; o < 8; ++o) u[o] = 0.0f;
        #pragma unroll
        for (int i = 0; i < 8; ++i) {
            const float4 w0 = *(const float4*)&wlds[lrow][i * 16 + ohs + 0];
            const float4 w1 = *(const float4*)&wlds[lrow][i * 16 + ohs + 4];
            const float x = xi[i];
            u[0] = fmaf(x, w0.x, u[0]);  u[1] = fmaf(x, w0.y, u[1]);
            u[2] = fmaf(x, w0.z, u[2]);  u[3] = fmaf(x, w0.w, u[3]);
            u[4] = fmaf(x, w1.x, u[4]);  u[5] = fmaf(x, w1.y, u[5]);
            u[6] = fmaf(x, w1.z, u[6]);  u[7] = fmaf(x, w1.w, u[7]);
        }
        *(float4*)(ubase + (size_t)rr * On)     = make_float4(u[0], u[1], u[2], u[3]);
        *(float4*)(ubase + (size_t)rr * On + 4) = make_float4(u[4], u[5], u[6], u[7]);
        #pragma unroll
        for (int o = 0; o < 8; ++o) tacc[o] += u[o];
        xa = nxa; xb = nxb;
    }

    __syncthreads();   // done reading wlds; smem becomes red

    #pragma unroll
    for (int o = 0; o < 8; ++o) red[w][lane][o] = tacc[o];
    __syncthreads();

    {
        const int oh2  = tid >> 8;
        const int rem2 = tid & 255;
        const int bl   = rem2 >> 2;
        const int oq   = rem2 & 3;
        const int bg   = bh * 64 + bl;
        const int idx = c * BO + bg * On + oh2 * 8 + oq * 2;
        #pragma unroll
        for (int q = 0; q < 2; ++q) {
            const int o = oq * 2 + q;
            atomicAdd(T1 + idx + q,
                      red[oh2*4+0][bl][o] + red[oh2*4+1][bl][o] +
                      red[oh2*4+2][bl][o] + red[oh2*4+3][bl][o]);
        }
    }
}

// ---- stream passes 2/3: pure coalesced reduction over materialized u --------
// One wave per (c,b) row; lane = (r mod 16, o-group); full r-reduction in-wave.
template<int PASS>
__global__ __launch_bounds__(NT2)
void stream_pass(const float* __restrict__ U, float* __restrict__ TL,
                 float* __restrict__ out)
{
    __shared__ float sA[4], sB[4];
    __shared__ int sdone;
    float* T1 = TL;
    float* T2 = TL + CBO;
    float* L2 = TL + 2 * CBO;
    float* T3 = TL + 3 * CBO;
    float* L3 = TL + 4 * CBO;
    unsigned* ticket = (unsigned*)(TL + 5 * CBO);

    const int tid  = threadIdx.x;
    const int blk  = blockIdx.x;
    const int w    = tid >> 6;
    const int lane = tid & 63;
    const int og   = lane & 3;

    // ---- redundant in-block n2 scan(s)
    float n2a = 0.f, n2b = 0.f;
    {
        const float4* T1v = (const float4*)T1;
        if (PASS == 2) {
            for (int i = tid; i < 5120; i += NT2) {
                float4 v = T1v[i];
                float s0 = v.x*INV_R, s1 = v.y*INV_R, s2 = v.z*INV_R, s3 = v.w*INV_R;
                n2a += s0*s0 + s1*s1 + s2*s2 + s3*s3;
            }
        } else {
            const float4* T2v = (const float4*)T2;
            const float4* L2v = (const float4*)L2;
            for (int i = tid; i < 5120; i += NT2) {
                float4 v = T1v[i];
                float s0 = v.x*INV_R, s1 = v.y*INV_R, s2 = v.z*INV_R, s3 = v.w*INV_R;
                n2a += s0*s0 + s1*s1 + s2*s2 + s3*s3;
                float4 t = T2v[i], l = L2v[i];
                float q0 = t.x/l.x, q1 = t.y/l.y, q2 = t.z/l.z, q3 = t.w/l.w;
                n2b += q0*q0 + q1*q1 + q2*q2 + q3*q3;
            }
        }
        #pragma unroll
        for (int d = 1; d < 64; d <<= 1) {
            n2a += __shfl_xor(n2a, d);
            n2b += __shfl_xor(n2b, d);
        }
        if (lane == 0) { sA[w] = n2a; sB[w] = n2b; }
        __syncthreads();
        n2a = sA[0] + sA[1] + sA[2] + sA[3];
        n2b = sB[0] + sB[1] + sB[2] + sB[3];
    }

    const int row = blk * 4 + w;          // 0..1279 = (c,b)
    const float c1 = n2a / ((1.f + n2a) * sqrtf(n2a)) * (LOG2E * INV_R);

    float4 vsv;
    {
        float4 t1 = *(const float4*)(T1 + row * On + og * 4);
        vsv.x = c1 * t1.x; vsv.y = c1 * t1.y; vsv.z = c1 * t1.z; vsv.w = c1 * t1.w;
        if (PASS == 3) {
            const float c2 = n2b / ((1.f + n2b) * sqrtf(n2b)) * LOG2E;
            float4 t2 = *(const float4*)(T2 + row * On + og * 4);
            float4 l2 = *(const float4*)(L2 + row * On + og * 4);
            vsv.x += c2 * (t2.x / l2.x); vsv.y += c2 * (t2.y / l2.y);
            vsv.z += c2 * (t2.z / l2.z); vsv.w += c2 * (t2.w / l2.w);
        }
    }

    // ---- stream this row's u tile: 4608 float4, fully coalesced
    const float4* Uv = (const float4*)(U + (size_t)row * UROW);
    float4 Ta = make_float4(0.f,0.f,0.f,0.f), La = make_float4(0.f,0.f,0.f,0.f);
    #pragma unroll 8
    for (int k = 0; k < 72; ++k) {
        const float4 uv = Uv[k * 64 + lane];
        const float e0 = exp2f(uv.x * vsv.x);
        const float e1 = exp2f(uv.y * vsv.y);
        const float e2 = exp2f(uv.z * vsv.z);
        const float e3 = exp2f(uv.w * vsv.w);
        Ta.x = fmaf(e0, uv.x, Ta.x); La.x += e0;
        Ta.y = fmaf(e1, uv.y, Ta.y); La.y += e1;
        Ta.z = fmaf(e2, uv.z, Ta.z); La.z += e2;
        Ta.w = fmaf(e3, uv.w, Ta.w); La.w += e3;
    }
    // reduce over the 16 r-lane groups (lanes sharing og)
    #pragma unroll
    for (int d = 4; d < 64; d <<= 1) {
        Ta.x += __shfl_xor(Ta.x, d); Ta.y += __shfl_xor(Ta.y, d);
        Ta.z += __shfl_xor(Ta.z, d); Ta.w += __shfl_xor(Ta.w, d);
        La.x += __shfl_xor(La.x, d); La.y += __shfl_xor(La.y, d);
        La.z += __shfl_xor(La.z, d); La.w += __shfl_xor(La.w, d);
    }
    float* Ts = (PASS == 2) ? T2 : T3;
    float* Ls = (PASS == 2) ? L2 : L3;
    if (lane < 4) {
        *(float4*)(Ts + row * On + lane * 4) = Ta;
        *(float4*)(Ls + row * On + lane * 4) = La;
    }

    // ---- PASS 3: last block computes n2_3 and writes the output
    if (PASS == 3) {
        __syncthreads();
        if (tid == 0) {
            __threadfence();
            sdone = (atomicAdd(ticket, 1u) == NBLK2 - 1);
        }
        __syncthreads();
        if (sdone) {
            __threadfence();
            const float4* T3v = (const float4*)T3;
            const float4* L3v = (const float4*)L3;
            float acc = 0.f;
            for (int i = tid; i < 5120; i += NT2) {
                float4 t = T3v[i], l = L3v[i];
                float s0 = t.x/l.x, s1 = t.y/l.y, s2 = t.z/l.z, s3 = t.w/l.w;
                acc += s0*s0 + s1*s1 + s2*s2 + s3*s3;
            }
            #pragma unroll
            for (int d = 1; d < 64; d <<= 1) acc += __shfl_xor(acc, d);
            if (lane == 0) sA[w] = acc;
            __syncthreads();
            const float n2 = sA[0] + sA[1] + sA[2] + sA[3];
            const float c3 = n2 / ((1.f + n2) * sqrtf(n2));
            for (int i = tid; i < 5120; i += NT2) {
                float4 t = T3v[i], l = L3v[i];
                float4 o4;
                o4.x = c3 * t.x / l.x; o4.y = c3 * t.y / l.y;
                o4.z = c3 * t.z / l.z; o4.w = c3 * t.w / l.w;
                ((float4*)out)[i] = o4;
            }
        }
    }
}

extern "C" void kernel_launch(void* const* d_in, const int* in_sizes, int n_in,
                              void* d_out, int out_size, void* d_ws, size_t ws_size,
                              hipStream_t stream)
{
    const float* X = (const float*)d_in[0];
    const float* W = (const float*)d_in[1];
    float* ws = (float*)d_ws;
    float* XT = ws;                          // 1,179,648 floats (4.7 MB)
    float* TL = XT + Rn * Bn * CIn;          // 102,416 floats
    float* U  = TL + 102416;                 // 23,592,960 floats (94.4 MB)
    float* out = (float*)d_out;

    transpose_x<<<Rn, 256, 0, stream>>>(X, XT, TL);
    pass1_kernel<<<GRID1, NT1, 0, stream>>>(XT, W, TL, U);
    stream_pass<2><<<NBLK2, NT2, 0, stream>>>(U, TL, out);
    stream_pass<3><<<NBLK2, NT2, 0, stream>>>(U, TL, out);
}

// Round 10
// 146.820 us; speedup vs baseline: 1.2950x; 1.2950x over previous
//
#include <hip/hip_runtime.h>
#include <math.h>

#define Bn   128
#define Rn   1152
#define CIn  8
#define Cn   10
#define On   16
#define BO   2048      // Bn*On
#define CBO  20480     // Cn*BO
#define RC   12        // r's per r-seg wave (pass1)
#define GRID1 480      // 10c * 2bh * 24segq
#define NT1  512       // pass1: 8 waves = 4 r-segs x 2 o-halves
#define GRID2 320      // stream: 10c * 2bh * 2oh * 8cg
#define NT2  512       // 8 waves = 8 r-subchunks
#define LOG2E 1.4426950408889634f
#define INV_R 8.6805555e-4f   // 1/1152

// ws: XT[1179648] | TL[102416] | U[23592960]
// TL: T1|T2|L2|T3|L3 (20480 each) | ticket
// U layout: [c][bh][r][oh][b:64][o:8]  -> wave writes/reads 2KB contiguous

// ---- transpose x[b][r][i] -> XT[r][g][b][q] + zero TL/ticket
__global__ __launch_bounds__(256)
void transpose_x(const float* __restrict__ X, float* __restrict__ XT,
                 float* __restrict__ TL)
{
    const int r = blockIdx.x;
    const int b = threadIdx.x & 127;
    const int g = threadIdx.x >> 7;
    float4 v = *(const float4*)(X + (size_t)b * (Rn * CIn) + r * CIn + g * 4);
    ((float4*)XT)[r * 256 + g * 128 + b] = v;
    const int zi = blockIdx.x * 256 + threadIdx.x;
    if (zi < 25604) ((float4*)TL)[zi] = make_float4(0.f, 0.f, 0.f, 0.f);
}

// ---- pass1: compute u, store coalesced, atomic-merge T1 --------------------
__global__ __launch_bounds__(NT1, 4)
void pass1_kernel(const float* __restrict__ XT, const float* __restrict__ W,
                  float* __restrict__ TL, float* __restrict__ U)
{
    __shared__ __align__(16) float smem[6144];          // W[48][128] = 24 KB
    float (*wlds)[128]  = (float (*)[128])smem;
    float (*red)[64][9] = (float (*)[64][9])smem;       // 18.4 KB overlay
    float* T1 = TL;

    const int blk  = blockIdx.x;
    const int c    = blk / 48;
    const int rem  = blk - c * 48;
    const int bh   = rem / 24;
    const int segq = rem - bh * 24;
    const int tid  = threadIdx.x;
    const int w    = tid >> 6;
    const int lane = tid & 63;
    const int b    = bh * 64 + lane;
    const int oh   = w >> 2;
    const int sw   = w & 3;
    const int ohs  = __builtin_amdgcn_readfirstlane(oh * 8);

    {
        const float4* gw4 = (const float4*)(W + (size_t)(c * Rn + segq * 48) * 128);
        float4* sw4 = (float4*)smem;
        #pragma unroll
        for (int k = 0; k < 3; ++k)
            sw4[tid + k * 512] = gw4[tid + k * 512];
    }

    float tacc[8];
    #pragma unroll
    for (int o = 0; o < 8; ++o) tacc[o] = 0.0f;

    __syncthreads();

    const float4* XT4 = (const float4*)XT;
    const int r0 = segq * 48 + sw * RC;
    const float4* xp = XT4 + (size_t)r0 * 256 + b;
    // coalesced U base: lane stride 32B, r stride 1024 floats
    float* ub = U + ((size_t)(c * 2 + bh) * Rn + r0) * 1024 + oh * 512 + lane * 8;

    float4 xa = xp[0];
    float4 xb = xp[128];
    for (int rr = 0; rr < RC; ++rr) {
        const int nx = (rr + 1 < RC) ? (rr + 1) : rr;
        const float4 nxa = xp[nx * 256];
        const float4 nxb = xp[nx * 256 + 128];
        const int lrow = sw * RC + rr;
        const float xi[8] = { xa.x, xa.y, xa.z, xa.w, xb.x, xb.y, xb.z, xb.w };

        float u[8];
        #pragma unroll
        for (int o = 0; o < 8; ++o) u[o] = 0.0f;
        #pragma unroll
        for (int i = 0; i < 8; ++i) {
            const float4 w0 = *(const float4*)&wlds[lrow][i * 16 + ohs + 0];
            const float4 w1 = *(const float4*)&wlds[lrow][i * 16 + ohs + 4];
            const float x = xi[i];
            u[0] = fmaf(x, w0.x, u[0]);  u[1] = fmaf(x, w0.y, u[1]);
            u[2] = fmaf(x, w0.z, u[2]);  u[3] = fmaf(x, w0.w, u[3]);
            u[4] = fmaf(x, w1.x, u[4]);  u[5] = fmaf(x, w1.y, u[5]);
            u[6] = fmaf(x, w1.z, u[6]);  u[7] = fmaf(x, w1.w, u[7]);
        }
        *(float4*)(ub + (size_t)rr * 1024)     = make_float4(u[0], u[1], u[2], u[3]);
        *(float4*)(ub + (size_t)rr * 1024 + 4) = make_float4(u[4], u[5], u[6], u[7]);
        #pragma unroll
        for (int o = 0; o < 8; ++o) tacc[o] += u[o];
        xa = nxa; xb = nxb;
    }

    __syncthreads();
    #pragma unroll
    for (int o = 0; o < 8; ++o) red[w][lane][o] = tacc[o];
    __syncthreads();

    {
        const int bl = tid >> 3;          // 0..63
        const int oq = tid & 7;           // 0..7
        #pragma unroll
        for (int oh2 = 0; oh2 < 2; ++oh2) {
            const float s = red[oh2*4+0][bl][oq] + red[oh2*4+1][bl][oq] +
                            red[oh2*4+2][bl][oq] + red[oh2*4+3][bl][oq];
            atomicAdd(T1 + c * BO + (bh * 64 + bl) * On + oh2 * 8 + oq, s);
        }
    }
}

// ---- stream passes 2/3: coalesced per-lane reduction over u ----------------
// block = (c, bh, oh, cg); 8 waves = 8 r-subchunks of 18 r's; lane = b.
template<int PASS>
__global__ __launch_bounds__(NT2, 4)
void stream_pass(const float* __restrict__ U, float* __restrict__ TL,
                 float* __restrict__ out)
{
    __shared__ float sm[8][64][18];     // 36.9 KB cross-wave merge
    __shared__ float sA[8], sB[8];
    __shared__ int sdone;
    float* T1 = TL;
    float* T2 = TL + CBO;
    float* L2 = TL + 2 * CBO;
    float* T3 = TL + 3 * CBO;
    float* L3 = TL + 4 * CBO;
    unsigned* ticket = (unsigned*)(TL + 5 * CBO);

    const int blk  = blockIdx.x;
    const int c    = blk / 32;
    const int rem  = blk & 31;
    const int bh   = rem >> 4;
    const int oh   = (rem >> 3) & 1;
    const int cg   = rem & 7;
    const int tid  = threadIdx.x;
    const int w    = tid >> 6;
    const int lane = tid & 63;

    // ---- redundant in-block n2 scan(s)
    float n2a = 0.f, n2b = 0.f;
    {
        const float4* T1v = (const float4*)T1;
        if (PASS == 2) {
            for (int i = tid; i < 5120; i += NT2) {
                float4 v = T1v[i];
                float s0 = v.x*INV_R, s1 = v.y*INV_R, s2 = v.z*INV_R, s3 = v.w*INV_R;
                n2a += s0*s0 + s1*s1 + s2*s2 + s3*s3;
            }
        } else {
            const float4* T2v = (const float4*)T2;
            const float4* L2v = (const float4*)L2;
            for (int i = tid; i < 5120; i += NT2) {
                float4 v = T1v[i];
                float s0 = v.x*INV_R, s1 = v.y*INV_R, s2 = v.z*INV_R, s3 = v.w*INV_R;
                n2a += s0*s0 + s1*s1 + s2*s2 + s3*s3;
                float4 t = T2v[i], l = L2v[i];
                float q0 = t.x/l.x, q1 = t.y/l.y, q2 = t.z/l.z, q3 = t.w/l.w;
                n2b += q0*q0 + q1*q1 + q2*q2 + q3*q3;
            }
        }
        #pragma unroll
        for (int d = 1; d < 64; d <<= 1) {
            n2a += __shfl_xor(n2a, d);
            n2b += __shfl_xor(n2b, d);
        }
        if (lane == 0) { sA[w] = n2a; sB[w] = n2b; }
        __syncthreads();
        n2a = sA[0]+sA[1]+sA[2]+sA[3]+sA[4]+sA[5]+sA[6]+sA[7];
        n2b = sB[0]+sB[1]+sB[2]+sB[3]+sB[4]+sB[5]+sB[6]+sB[7];
    }

    // ---- per-lane vs[8]
    const float c1 = n2a / ((1.f + n2a) * sqrtf(n2a)) * (LOG2E * INV_R);
    const int vbase = c * BO + (bh * 64 + lane) * On + oh * 8;
    float vs[8];
    {
        float4 a = *(const float4*)(T1 + vbase);
        float4 bq = *(const float4*)(T1 + vbase + 4);
        vs[0]=c1*a.x; vs[1]=c1*a.y; vs[2]=c1*a.z; vs[3]=c1*a.w;
        vs[4]=c1*bq.x; vs[5]=c1*bq.y; vs[6]=c1*bq.z; vs[7]=c1*bq.w;
        if (PASS == 3) {
            const float c2 = n2b / ((1.f + n2b) * sqrtf(n2b)) * LOG2E;
            float4 t0 = *(const float4*)(T2 + vbase);
            float4 t1 = *(const float4*)(T2 + vbase + 4);
            float4 l0 = *(const float4*)(L2 + vbase);
            float4 l1 = *(const float4*)(L2 + vbase + 4);
            vs[0] += c2*(t0.x/l0.x); vs[1] += c2*(t0.y/l0.y);
            vs[2] += c2*(t0.z/l0.z); vs[3] += c2*(t0.w/l0.w);
            vs[4] += c2*(t1.x/l1.x); vs[5] += c2*(t1.y/l1.y);
            vs[6] += c2*(t1.z/l1.z); vs[7] += c2*(t1.w/l1.w);
        }
    }

    // ---- stream 18 r's, 2-deep prefetch, per-lane accumulate (no shuffles)
    const int r0 = (cg * 8 + w) * 18;
    const float* ub = U + ((size_t)(c * 2 + bh) * Rn + r0) * 1024 + oh * 512 + lane * 8;
    float T[8], L[8];
    #pragma unroll
    for (int o = 0; o < 8; ++o) { T[o] = 0.f; L[o] = 0.f; }

    float4 u0 = *(const float4*)(ub);
    float4 u1 = *(const float4*)(ub + 4);
    for (int rr = 0; rr < 18; ++rr) {
        const int nx = (rr + 1 < 18) ? (rr + 1) : rr;
        const float4 p0 = *(const float4*)(ub + (size_t)nx * 1024);
        const float4 p1 = *(const float4*)(ub + (size_t)nx * 1024 + 4);
        const float uu[8] = { u0.x,u0.y,u0.z,u0.w, u1.x,u1.y,u1.z,u1.w };
        #pragma unroll
        for (int o = 0; o < 8; ++o) {
            const float e = exp2f(uu[o] * vs[o]);
            L[o] += e;
            T[o] = fmaf(e, uu[o], T[o]);
        }
        u0 = p0; u1 = p1;
    }

    // ---- cross-wave merge in LDS, then atomicAdd
    #pragma unroll
    for (int o = 0; o < 8; ++o) { sm[w][lane][o] = T[o]; sm[w][lane][8+o] = L[o]; }
    __syncthreads();
    {
        const int bl = tid >> 3;
        const int oq = tid & 7;
        float sT = 0.f, sL = 0.f;
        #pragma unroll
        for (int k = 0; k < 8; ++k) {
            sT += sm[k][bl][oq];
            sL += sm[k][bl][8+oq];
        }
        float* Ts = (PASS == 2) ? T2 : T3;
        float* Ls = (PASS == 2) ? L2 : L3;
        const int idx = c * BO + (bh * 64 + bl) * On + oh * 8 + oq;
        atomicAdd(Ts + idx, sT);
        atomicAdd(Ls + idx, sL);
    }

    // ---- PASS 3: last block computes n2_3 and writes output
    if (PASS == 3) {
        __syncthreads();
        if (tid == 0) {
            __threadfence();
            sdone = (atomicAdd(ticket, 1u) == GRID2 - 1);
        }
        __syncthreads();
        if (sdone) {
            __threadfence();
            const float4* T3v = (const float4*)T3;
            const float4* L3v = (const float4*)L3;
            float acc = 0.f;
            for (int i = tid; i < 5120; i += NT2) {
                float4 t = T3v[i], l = L3v[i];
                float s0 = t.x/l.x, s1 = t.y/l.y, s2 = t.z/l.z, s3 = t.w/l.w;
                acc += s0*s0 + s1*s1 + s2*s2 + s3*s3;
            }
            #pragma unroll
            for (int d = 1; d < 64; d <<= 1) acc += __shfl_xor(acc, d);
            if (lane == 0) sA[w] = acc;
            __syncthreads();
            const float n2 = sA[0]+sA[1]+sA[2]+sA[3]+sA[4]+sA[5]+sA[6]+sA[7];
            const float c3 = n2 / ((1.f + n2) * sqrtf(n2));
            for (int i = tid; i < 5120; i += NT2) {
                float4 t = T3v[i], l = L3v[i];
                float4 o4;
                o4.x = c3 * t.x / l.x; o4.y = c3 * t.y / l.y;
                o4.z = c3 * t.z / l.z; o4.w = c3 * t.w / l.w;
                ((float4*)out)[i] = o4;
            }
        }
    }
}

extern "C" void kernel_launch(void* const* d_in, const int* in_sizes, int n_in,
                              void* d_out, int out_size, void* d_ws, size_t ws_size,
                              hipStream_t stream)
{
    const float* X = (const float*)d_in[0];
    const float* W = (const float*)d_in[1];
    float* ws = (float*)d_ws;
    float* XT = ws;                          // 1,179,648 floats
    float* TL = XT + Rn * Bn * CIn;          // 102,416 floats
    float* U  = TL + 102416;                 // 23,592,960 floats (94.4 MB)
    float* out = (float*)d_out;

    transpose_x<<<Rn, 256, 0, stream>>>(X, XT, TL);
    pass1_kernel<<<GRID1, NT1, 0, stream>>>(XT, W, TL, U);
    stream_pass<2><<<GRID2, NT2, 0, stream>>>(U, TL, out);
    stream_pass<3><<<GRID2, NT2, 0, stream>>>(U, TL, out);
}

// Round 11
// 136.253 us; speedup vs baseline: 1.3955x; 1.0776x over previous
//
#include <hip/hip_runtime.h>
#include <math.h>

#define Bn   128
#define Rn   1152
#define CIn  8
#define Cn   10
#define On   16
#define BO   2048      // Bn*On
#define CBO  20480     // Cn*BO
#define RC   6         // r's per r-seg wave
#define PSEG 48        // partial segments
#define GRID 960       // 10c * 2bh * 48segq  -> ~3.75 blocks/CU
#define NTHR 512       // 8 waves = 4 r-segs x 2 o-halves

// ws layout: XT[1179648] | N2[4] | PT[48*CBO] | PL[48*CBO] | S[3*CBO]

// ---- transpose x[b][r][i] -> XT[r][g][b][q]  (i = g*4+q), float4 units
__global__ __launch_bounds__(256)
void transpose_x(const float* __restrict__ X, float* __restrict__ XT)
{
    const int r = blockIdx.x;
    const int b = threadIdx.x & 127;
    const int g = threadIdx.x >> 7;
    float4 v = *(const float4*)(X + (size_t)b * (Rn * CIn) + r * CIn + g * 4);
    ((float4*)XT)[r * 256 + g * 128 + b] = v;
}

// ---- pass kernel: W tile vector-staged into LDS (no scalar-cache path),
//      o split across waves (8 o's/thread), plain partial stores (no atomics).
template<int PASS>
__global__ __launch_bounds__(NTHR, 4)
void pass_kernel(const float* __restrict__ XT, const float* __restrict__ W,
                 const float* __restrict__ Sprev, const float* __restrict__ N2,
                 float* __restrict__ PT, float* __restrict__ PL)
{
    __shared__ __align__(16) float smem[8 * 64 * 18];   // 36.9 KB
    float (*wlds)[128]   = (float (*)[128])smem;        // W[24][128] = 12 KB
    float (*red)[64][18] = (float (*)[64][18])smem;     // overlay after loop

    const int blk  = blockIdx.x;
    const int c    = blk / 96;
    const int rem  = blk - c * 96;
    const int bh   = rem / 48;
    const int segq = rem - bh * 48;
    const int tid  = threadIdx.x;
    const int w    = tid >> 6;          // 0..7
    const int lane = tid & 63;
    const int b    = bh * 64 + lane;
    const int oh   = w >> 2;            // o-half
    const int sw   = w & 3;             // r-seg within block
    const int ohs  = __builtin_amdgcn_readfirstlane(oh * 8);

    // stage W tile: 24 rows * 128 floats = 768 float4 (vector path, parallel)
    {
        const float4* gw4 = (const float4*)(W + (size_t)(c * Rn + segq * 24) * 128);
        float4* sw4 = (float4*)smem;
        sw4[tid] = gw4[tid];
        if (tid < 256) sw4[512 + tid] = gw4[512 + tid];
    }

    // per-thread Vsum (pre-scaled by log2e) from previous passes, 8 o's
    float vs[8];
    if (PASS > 1) {
        float coef[PASS];
        #pragma unroll
        for (int t = 0; t < PASS - 1; ++t) {
            const float n2 = N2[t];
            coef[t] = n2 / ((1.0f + n2) * sqrtf(n2)) * 1.4426950408889634f;
        }
        const float* sp = Sprev + c * BO + b * On + ohs;
        #pragma unroll
        for (int q = 0; q < 2; ++q) {
            float4 a = make_float4(0.f, 0.f, 0.f, 0.f);
            #pragma unroll
            for (int t = 0; t < PASS - 1; ++t) {
                const float4 s4 = *(const float4*)(sp + t * CBO + q * 4);
                a.x = fmaf(coef[t], s4.x, a.x);
                a.y = fmaf(coef[t], s4.y, a.y);
                a.z = fmaf(coef[t], s4.z, a.z);
                a.w = fmaf(coef[t], s4.w, a.w);
            }
            vs[q * 4 + 0] = a.x; vs[q * 4 + 1] = a.y;
            vs[q * 4 + 2] = a.z; vs[q * 4 + 3] = a.w;
        }
    }

    float tacc[8], lacc[8];
    #pragma unroll
    for (int o = 0; o < 8; ++o) { tacc[o] = 0.0f; lacc[o] = 0.0f; }

    __syncthreads();   // W tile visible

    // ---- main loop: 6 r's, 1-deep x prefetch, broadcast ds_read for W
    const float4* XT4 = (const float4*)XT;
    const float4* xp  = XT4 + (size_t)(segq * 24 + sw * RC) * 256 + b;
    float4 xa = xp[0];
    float4 xb = xp[128];
    for (int rr = 0; rr < RC; ++rr) {
        const int nx = (rr + 1 < RC) ? (rr + 1) : rr;
        const float4 nxa = xp[nx * 256];
        const float4 nxb = xp[nx * 256 + 128];
        const int lrow = sw * RC + rr;            // 0..23, wave-uniform
        const float xi[8] = { xa.x, xa.y, xa.z, xa.w, xb.x, xb.y, xb.z, xb.w };

        float u[8];
        #pragma unroll
        for (int o = 0; o < 8; ++o) u[o] = 0.0f;
        #pragma unroll
        for (int i = 0; i < 8; ++i) {
            const float4 w0 = *(const float4*)&wlds[lrow][i * 16 + ohs + 0];
            const float4 w1 = *(const float4*)&wlds[lrow][i * 16 + ohs + 4];
            const float x = xi[i];
            u[0] = fmaf(x, w0.x, u[0]);  u[1] = fmaf(x, w0.y, u[1]);
            u[2] = fmaf(x, w0.z, u[2]);  u[3] = fmaf(x, w0.w, u[3]);
            u[4] = fmaf(x, w1.x, u[4]);  u[5] = fmaf(x, w1.y, u[5]);
            u[6] = fmaf(x, w1.z, u[6]);  u[7] = fmaf(x, w1.w, u[7]);
        }
        #pragma unroll
        for (int o = 0; o < 8; ++o) {
            if (PASS == 1) {
                tacc[o] += u[o];
            } else {
                const float e = exp2f(u[o] * vs[o]);
                lacc[o] += e;
                tacc[o] = fmaf(e, u[o], tacc[o]);
            }
        }
        xa = nxa; xb = nxb;
    }

    __syncthreads();   // done reading wlds; smem becomes red

    #pragma unroll
    for (int o = 0; o < 8; ++o) {
        red[w][lane][o] = tacc[o];
        if (PASS > 1) red[w][lane][8 + o] = lacc[o];
    }
    __syncthreads();

    // ---- block partials -> PT/PL (plain coalesced stores, no atomics)
    {
        const int oh2  = tid >> 8;        // which o-half to reduce
        const int rem2 = tid & 255;
        const int bl   = rem2 >> 2;       // 0..63
        const int oq   = rem2 & 3;        // 2 o's per thread
        const int bg   = bh * 64 + bl;
        float2 tv, lv;
        float* tp = (float*)&tv;
        float* lp = (float*)&lv;
        #pragma unroll
        for (int q = 0; q < 2; ++q) {
            const int o = oq * 2 + q;
            tp[q] = red[oh2*4+0][bl][o] + red[oh2*4+1][bl][o] +
                    red[oh2*4+2][bl][o] + red[oh2*4+3][bl][o];
            lp[q] = red[oh2*4+0][bl][8+o] + red[oh2*4+1][bl][8+o] +
                    red[oh2*4+2][bl][8+o] + red[oh2*4+3][bl][8+o];
        }
        const int idx = segq * CBO + c * BO + bg * On + oh2 * 8 + oq * 2;
        *(float2*)(PT + idx) = tv;
        if (PASS > 1) *(float2*)(PL + idx) = lv;
    }
}

// sum partials over PSEG segs; s = T/L; store S slot; reduce sum(s^2) -> N2 slot
template<int PASS>
__global__ __launch_bounds__(256)
void combine_kernel(const float* __restrict__ PT, const float* __restrict__ PL,
                    float* __restrict__ Sout, float* __restrict__ n2out)
{
    const int i = blockIdx.x * 256 + threadIdx.x;   // 80 blocks * 256 = 20480
    float T = 0.0f, L = 0.0f;
    #pragma unroll 8
    for (int s = 0; s < PSEG; ++s) T += PT[s * CBO + i];
    if (PASS == 1) {
        L = (float)Rn;
    } else {
        #pragma unroll 8
        for (int s = 0; s < PSEG; ++s) L += PL[s * CBO + i];
    }
    const float sv = T / L;
    Sout[i] = sv;
    float sq = sv * sv;
    #pragma unroll
    for (int d = 1; d < 64; d <<= 1) sq += __shfl_xor(sq, d);
    __shared__ float red[4];
    if ((threadIdx.x & 63) == 0) red[threadIdx.x >> 6] = sq;
    __syncthreads();
    if (threadIdx.x == 0)
        atomicAdd(n2out, red[0] + red[1] + red[2] + red[3]);
}

__global__ __launch_bounds__(256)
void final_kernel(const float* __restrict__ S, const float* __restrict__ n2p,
                  float* __restrict__ out)
{
    const int i = blockIdx.x * 256 + threadIdx.x;
    const float n2 = *n2p;
    const float coef = n2 / ((1.0f + n2) * sqrtf(n2));
    out[i] = coef * S[i];
}

extern "C" void kernel_launch(void* const* d_in, const int* in_sizes, int n_in,
                              void* d_out, int out_size, void* d_ws, size_t ws_size,
                              hipStream_t stream)
{
    const float* X = (const float*)d_in[0];
    const float* W = (const float*)d_in[1];
    float* ws = (float*)d_ws;
    float* XT = ws;                          // 1,179,648 floats (4.7 MB)
    float* N2 = XT + Rn * Bn * CIn;          // 4 floats
    float* PT = N2 + 4;                      // PSEG*CBO = 983,040
    float* PL = PT + PSEG * CBO;             // PSEG*CBO
    float* S  = PL + PSEG * CBO;             // 3*CBO

    hipMemsetAsync(N2, 0, 16, stream);       // zero n^2 accumulators only

    transpose_x<<<Rn, 256, 0, stream>>>(X, XT);
    pass_kernel<1><<<GRID, NTHR, 0, stream>>>(XT, W, S, N2, PT, PL);
    combine_kernel<1><<<80, 256, 0, stream>>>(PT, PL, S + 0 * CBO, N2 + 0);
    pass_kernel<2><<<GRID, NTHR, 0, stream>>>(XT, W, S, N2, PT, PL);
    combine_kernel<2><<<80, 256, 0, stream>>>(PT, PL, S + 1 * CBO, N2 + 1);
    pass_kernel<3><<<GRID, NTHR, 0, stream>>>(XT, W, S, N2, PT, PL);
    combine_kernel<3><<<80, 256, 0, stream>>>(PT, PL, S + 2 * CBO, N2 + 2);
    final_kernel<<<80, 256, 0, stream>>>(S + 2 * CBO, N2 + 2, (float*)d_out);
}